// Round 7
// baseline (284.797 us; speedup 1.0000x reference)
//
#include <hip/hip_runtime.h>
#include <hip/hip_bf16.h>
#include <stdint.h>

typedef __attribute__((ext_vector_type(8))) __bf16 bf16x8;
typedef __attribute__((ext_vector_type(4))) float f32x4;
typedef __attribute__((ext_vector_type(4))) unsigned int u32x4;

#define BM 256
#define BN 256
#define BKT 32              // K per ring slot
#define SLOT 16384          // 256 rows x 32 cols x 2B
// ring-5: slots for tiles T..T+4 ; LDS = 5*(16K+16K) = 160 KiB (CU max)

// ---------------- NVFP4 quantize-dequantize (factored: no global scale) ----------------

__device__ __forceinline__ float fp8_e4m3_rne(float x) {
  if (x < 0.015625f) {                       // below min normal 2^-6: subnormal grid 2^-9
    return rintf(x * 512.0f) * 0.001953125f;
  }
  uint32_t u = __float_as_uint(x);
  uint32_t keep = u & 0xFFF00000u;
  uint32_t rem  = u & 0x000FFFFFu;
  uint32_t lsb  = (u >> 20) & 1u;
  if (rem > 0x80000u || (rem == 0x80000u && lsb)) keep += 0x100000u;
  return __uint_as_float(keep);
}

__device__ __forceinline__ float snap_lvl(float a) {
  if (a > 5.0f)  return 6.0f;
  if (a > 3.5f)  return 4.0f;
  if (a > 2.5f)  return 3.0f;
  if (a > 1.75f) return 2.0f;
  if (a > 1.25f) return 1.5f;
  if (a > 0.75f) return 1.0f;
  if (a > 0.25f) return 0.5f;
  return 0.0f;
}

__global__ __launch_bounds__(256) void quant_nvfp4(
    const float* __restrict__ in, unsigned short* __restrict__ out,
    const float* __restrict__ gsp, int nblk) {
  int b = blockIdx.x * 256 + threadIdx.x;
  if (b >= nblk) return;
  float gs = gsp[0];
  const float4* p = reinterpret_cast<const float4*>(in) + (size_t)b * 4;
  float v[16];
#pragma unroll
  for (int i = 0; i < 4; ++i) {
    float4 t4 = p[i];
    v[i * 4 + 0] = t4.x; v[i * 4 + 1] = t4.y;
    v[i * 4 + 2] = t4.z; v[i * 4 + 3] = t4.w;
  }
  float amax = 0.0f;
#pragma unroll
  for (int i = 0; i < 16; ++i) amax = fmaxf(amax, fabsf(v[i]));
  float bs8 = fp8_e4m3_rne(amax / (6.0f * gs));
  float scale = fmaxf(bs8 * gs, 1e-12f);
  unsigned short o[16];
#pragma unroll
  for (int i = 0; i < 16; ++i) {
    float q = v[i] / scale;
    float a = fminf(fabsf(q), 6.0f);
    float val = copysignf(snap_lvl(a) * bs8, q);
    o[i] = (unsigned short)(__float_as_uint(val) >> 16);
  }
  uint4 w0 = make_uint4((uint32_t)o[0] | ((uint32_t)o[1] << 16),
                        (uint32_t)o[2] | ((uint32_t)o[3] << 16),
                        (uint32_t)o[4] | ((uint32_t)o[5] << 16),
                        (uint32_t)o[6] | ((uint32_t)o[7] << 16));
  uint4 w1 = make_uint4((uint32_t)o[8]  | ((uint32_t)o[9]  << 16),
                        (uint32_t)o[10] | ((uint32_t)o[11] << 16),
                        (uint32_t)o[12] | ((uint32_t)o[13] << 16),
                        (uint32_t)o[14] | ((uint32_t)o[15] << 16));
  uint4* op = reinterpret_cast<uint4*>(out + (size_t)b * 16);
  op[0] = w0;
  op[1] = w1;
}

// ---------------- bf16 GEMM, C = A * B^T ; 256x256 tile, ring-5, cross-phase prefetch ----------------

__device__ __forceinline__ void async_lds16(const void* g, void* l) {
  __builtin_amdgcn_global_load_lds((__attribute__((address_space(1))) void*)(g),
                                   (__attribute__((address_space(3))) void*)(l),
                                   16, 0, 0);
}

#define DSR(dst, a) asm volatile("ds_read_b128 %0, %1" : "=v"(dst) : "v"(a))
#define LGKM(N) do { asm volatile("s_waitcnt lgkmcnt(" #N ")" ::: "memory"); \
                     __builtin_amdgcn_sched_barrier(0); } while (0)
#define VMC(S) asm volatile("s_waitcnt vmcnt(" S ")" ::: "memory")
#define BCB(x) __builtin_bit_cast(bf16x8, x)

#define MF4(mi, ar, b0, b1, b2, b3) do {                                       \
    acc[mi][0] = __builtin_amdgcn_mfma_f32_16x16x32_bf16(BCB(ar), BCB(b0), acc[mi][0], 0, 0, 0); \
    acc[mi][1] = __builtin_amdgcn_mfma_f32_16x16x32_bf16(BCB(ar), BCB(b1), acc[mi][1], 0, 0, 0); \
    acc[mi][2] = __builtin_amdgcn_mfma_f32_16x16x32_bf16(BCB(ar), BCB(b2), acc[mi][2], 0, 0, 0); \
    acc[mi][3] = __builtin_amdgcn_mfma_f32_16x16x32_bf16(BCB(ar), BCB(b3), acc[mi][3], 0, 0, 0); \
  } while (0)

// staging units, issue order per tile = consumption order: [A-lo, B-lo, B-hi, A-hi]
#define STG_A1(tile, so) async_lds16(pA0 + (size_t)(tile) * BKT, (char*)As + (so) + lo0)
#define STG_B1(tile, so) async_lds16(pB0 + (size_t)(tile) * BKT, (char*)Bs + (so) + lo0)
#define STG_B2(tile, so) async_lds16(pB1 + (size_t)(tile) * BKT, (char*)Bs + (so) + lo1)
#define STG_A2(tile, so) async_lds16(pA1 + (size_t)(tile) * BKT, (char*)As + (so) + lo1)

// One K32 tile, 2 phases. Entering: aC=A(T).m0-3, bX=B(T) (read last tile).
// P1: gate; stage(T+3 lo); read A(T).m4-7; lgkm(4); MFMA acc[0-3] (aC x bX).
// P2: gate; stage(T+3 hi); read B(T+1)->bY, A(T+1).m0-3->aC; lgkm(8); MFMA acc[4-7] (nA x bX).
#define TILE(VM1, VM2, DO_S, sCur, sNxt, sStg, stgT, RN,                       \
             bX0, bX1, bX2, bX3, bY0, bY1, bY2, bY3) do {                      \
    VMC(VM1);                                                                  \
    __builtin_amdgcn_s_barrier();                                              \
    if (DO_S) { STG_A1(stgT, sStg); STG_B1(stgT, sStg); }                      \
    DSR(nA0, adA[4] + (sCur)); DSR(nA1, adA[5] + (sCur));                      \
    DSR(nA2, adA[6] + (sCur)); DSR(nA3, adA[7] + (sCur));                      \
    __builtin_amdgcn_sched_barrier(0);                                         \
    LGKM(4);                                                                   \
    __builtin_amdgcn_s_setprio(1);                                             \
    MF4(0, aC0, bX0, bX1, bX2, bX3);                                           \
    MF4(1, aC1, bX0, bX1, bX2, bX3);                                           \
    MF4(2, aC2, bX0, bX1, bX2, bX3);                                           \
    MF4(3, aC3, bX0, bX1, bX2, bX3);                                           \
    __builtin_amdgcn_s_setprio(0);                                             \
    __builtin_amdgcn_sched_barrier(0);                                         \
    VMC(VM2);                                                                  \
    __builtin_amdgcn_s_barrier();                                              \
    if (DO_S) { STG_B2(stgT, sStg); STG_A2(stgT, sStg); }                      \
    if (RN) {                                                                  \
      DSR(bY0, adB[0] + (sNxt)); DSR(bY1, adB[1] + (sNxt));                    \
      DSR(bY2, adB[2] + (sNxt)); DSR(bY3, adB[3] + (sNxt));                    \
      DSR(aC0, adA[0] + (sNxt)); DSR(aC1, adA[1] + (sNxt));                    \
      DSR(aC2, adA[2] + (sNxt)); DSR(aC3, adA[3] + (sNxt));                    \
    }                                                                          \
    __builtin_amdgcn_sched_barrier(0);                                         \
    if (RN) { LGKM(8); } else { LGKM(0); }                                     \
    __builtin_amdgcn_s_setprio(1);                                             \
    MF4(4, nA0, bX0, bX1, bX2, bX3);                                           \
    MF4(5, nA1, bX0, bX1, bX2, bX3);                                           \
    MF4(6, nA2, bX0, bX1, bX2, bX3);                                           \
    MF4(7, nA3, bX0, bX1, bX2, bX3);                                           \
    __builtin_amdgcn_s_setprio(0);                                             \
    __builtin_amdgcn_sched_barrier(0);                                         \
  } while (0)

__global__ __launch_bounds__(512, 2) void gemm_bt_bf16(
    const unsigned short* __restrict__ A, const unsigned short* __restrict__ B,
    const float* __restrict__ bias, const float* __restrict__ gsx,
    const float* __restrict__ gsw, float* __restrict__ C,
    int M, int N, int K) {
  __shared__ __align__(16) unsigned short As[5 * 8192];   // 80 KiB
  __shared__ __align__(16) unsigned short Bs[5 * 8192];   // 80 KiB

  const int t = threadIdx.x;
  const int l = t & 63;
  const int w = t >> 6;
  const int wm = w >> 2, wn = w & 3;     // 2x4 waves; wave tile = 128(M) x 64(N)

  // bijective XCD swizzle (nwg = 512, divisible by 8)
  const int nbn = N / BN;
  const int nwg = (M / BM) * nbn;
  const int cpx = nwg >> 3;
  int bid = blockIdx.x;
  int logical = (bid & 7) * cpx + (bid >> 3);
  const int bm = logical / nbn, bn = logical % nbn;
  const int brow = bm * BM, bcol = bn * BN;

  // ---- staging: linear LDS dest; source = inverse swizzle + A-row phase permutation ----
  // swizzle involution on slot byte q: q ^= ((q>>7)&3)<<4  (within-row, bits 4-5)
  // A-row permutation: LDS row r' <- global row g: r' = ((g%128)/64)*128 + (g/128)*64 + g%64
  //   => P1-half (m0-3 rows, both wm) = LDS rows 0-127 = gload unit A-lo; m4-7 = A-hi.
  unsigned int b0 = (unsigned int)t * 16u;
  unsigned int b1 = b0 + 8192u;
  unsigned int sp0 = b0 ^ (((b0 >> 7) & 3u) << 4);
  unsigned int sp1 = b1 ^ (((b1 >> 7) & 3u) << 4);
  const unsigned int lo0 = b0, lo1 = b1;
  unsigned int rA0 = b0 >> 6, rA1 = b1 >> 6;
  unsigned int gA0 = ((rA0 >> 6) & 1u) * 128u + (rA0 >> 7) * 64u + (rA0 & 63u);
  unsigned int gA1 = ((rA1 >> 6) & 1u) * 128u + (rA1 >> 7) * 64u + (rA1 & 63u);
  const unsigned short* pA0 = A + (size_t)(brow + gA0) * K + ((sp0 & 63u) >> 1);
  const unsigned short* pA1 = A + (size_t)(brow + gA1) * K + ((sp1 & 63u) >> 1);
  const unsigned short* pB0 = B + (size_t)(bcol + (b0 >> 6)) * K + ((sp0 & 63u) >> 1);
  const unsigned short* pB1 = B + (size_t)(bcol + (b1 >> 6)) * K + ((sp1 & 63u) >> 1);

  // ---- fragment read addresses (abs LDS addr, swizzled; A uses permuted rows) ----
  const unsigned baseAu = (unsigned)(uintptr_t)(&As[0]);
  const unsigned baseBu = (unsigned)(uintptr_t)(&Bs[0]);
  unsigned int adA[8], adB[4];
#pragma unroll
  for (int mi = 0; mi < 8; ++mi) {
    unsigned int rp = (unsigned)(mi >> 2) * 128u + (unsigned)wm * 64u +
                      (unsigned)(mi & 3) * 16u + (l & 15);
    unsigned int q = rp * 64u + (((unsigned)l >> 4) << 4);
    adA[mi] = baseAu + (q ^ (((q >> 7) & 3u) << 4));
  }
#pragma unroll
  for (int ni = 0; ni < 4; ++ni) {
    unsigned int r = (unsigned)wn * 64u + (unsigned)ni * 16u + (l & 15);
    unsigned int q = r * 64u + (((unsigned)l >> 4) << 4);
    adB[ni] = baseBu + (q ^ (((q >> 7) & 3u) << 4));
  }

  f32x4 acc[8][4] = {};
  u32x4 aC0, aC1, aC2, aC3;        // A(T).m0-3 (consumed P1)
  u32x4 nA0, nA1, nA2, nA3;        // A(T).m4-7 (read P1, consumed P2)
  u32x4 bP0, bP1, bP2, bP3;        // B ping
  u32x4 bQ0, bQ1, bQ2, bQ3;        // B pong

  // prologue: stage tiles 0,1,2 (order A-lo,B-lo,B-hi,A-hi each), then first reads
  STG_A1(0, 0);        STG_B1(0, 0);        STG_B2(0, 0);        STG_A2(0, 0);
  STG_A1(1, SLOT);     STG_B1(1, SLOT);     STG_B2(1, SLOT);     STG_A2(1, SLOT);
  STG_A1(2, 2 * SLOT); STG_B1(2, 2 * SLOT); STG_B2(2, 2 * SLOT); STG_A2(2, 2 * SLOT);
  VMC("9");                                   // confirm tile0 {A-lo, B-lo, B-hi}
  __builtin_amdgcn_s_barrier();
  DSR(bP0, adB[0]); DSR(bP1, adB[1]); DSR(bP2, adB[2]); DSR(bP3, adB[3]);
  DSR(aC0, adA[0]); DSR(aC1, adA[1]); DSR(aC2, adA[2]); DSR(aC3, adA[3]);
  __builtin_amdgcn_sched_barrier(0);

  // steady: 62 iterations x 2 tiles (tiles 0..123, stages 3..127... stgT max = 123+4=127)
  int sa = 0;
#pragma unroll 1
  for (int T = 0; T < 124; T += 2) {
    int sb = sa + SLOT; if (sb >= 5 * SLOT) sb -= 5 * SLOT;
    int s2 = sb + SLOT; if (s2 >= 5 * SLOT) s2 -= 5 * SLOT;
    int s3 = s2 + SLOT; if (s3 >= 5 * SLOT) s3 -= 5 * SLOT;
    int s4 = s3 + SLOT; if (s4 >= 5 * SLOT) s4 -= 5 * SLOT;
    TILE("8", "7", 1, sa, sb, s3, T + 3, 1,
         bP0, bP1, bP2, bP3, bQ0, bQ1, bQ2, bQ3);
    TILE("8", "7", 1, sb, s2, s4, T + 4, 1,
         bQ0, bQ1, bQ2, bQ3, bP0, bP1, bP2, bP3);
    sa = s2;
  }
  // tail: tiles 124(slot4),125(0),126(1),127(2); stage 127 during 124 -> slot 2
  TILE("8", "7", 1, 4 * SLOT, 0 * SLOT, 2 * SLOT, 127, 1,
       bP0, bP1, bP2, bP3, bQ0, bQ1, bQ2, bQ3);
  TILE("8", "5", 0, 0 * SLOT, 1 * SLOT, 0, 0, 1,
       bQ0, bQ1, bQ2, bQ3, bP0, bP1, bP2, bP3);
  TILE("4", "1", 0, 1 * SLOT, 2 * SLOT, 0, 0, 1,
       bP0, bP1, bP2, bP3, bQ0, bQ1, bQ2, bQ3);
  TILE("0", "0", 0, 2 * SLOT, 0, 0, 0, 0,
       bQ0, bQ1, bQ2, bQ3, bP0, bP1, bP2, bP3);

  // ---- epilogue ----
  const float gscale = gsx[0] * gsw[0];
  float bias_r[4];
#pragma unroll
  for (int ni = 0; ni < 4; ++ni)
    bias_r[ni] = bias[bcol + wn * 64 + ni * 16 + (l & 15)];
#pragma unroll
  for (int mi = 0; mi < 8; ++mi) {
#pragma unroll
    for (int ni = 0; ni < 4; ++ni) {
#pragma unroll
      for (int r = 0; r < 4; ++r) {
        int row = brow + wm * 128 + mi * 16 + (l >> 4) * 4 + r;
        int col = bcol + wn * 64 + ni * 16 + (l & 15);
        C[(size_t)row * N + col] = acc[mi][ni][r] * gscale + bias_r[ni];
      }
    }
  }
}

// ---------------- launch ----------------

extern "C" void kernel_launch(void* const* d_in, const int* in_sizes, int n_in,
                              void* d_out, int out_size, void* d_ws, size_t ws_size,
                              hipStream_t stream) {
  const float* x    = (const float*)d_in[0];
  const float* wgt  = (const float*)d_in[1];
  const float* bias = (const float*)d_in[2];
  const float* isc  = (const float*)d_in[3];
  const float* wsc  = (const float*)d_in[4];
  float* out = (float*)d_out;

  const int N = in_sizes[2];            // 4096
  const int K = in_sizes[1] / N;        // 4096
  const int M = in_sizes[0] / K;        // 8192

  unsigned short* Aq = (unsigned short*)d_ws;
  unsigned short* Bq = Aq + (size_t)M * K;

  int nblkA = M * K / 16;
  quant_nvfp4<<<(nblkA + 255) / 256, 256, 0, stream>>>(x, Aq, isc, nblkA);
  int nblkB = N * K / 16;
  quant_nvfp4<<<(nblkB + 255) / 256, 256, 0, stream>>>(wgt, Bq, wsc, nblkB);

  dim3 grid((M / BM) * (N / BN));
  gemm_bt_bf16<<<grid, 512, 0, stream>>>(Aq, Bq, bias, isc, wsc, out, M, N, K);
}